// Round 6
// baseline (126.533 us; speedup 1.0000x reference)
//
#include <hip/hip_runtime.h>
#include <stdint.h>

#define BB 8
#define CC 256
#define NN 4096
#define KK 16
#define NT 32              // n-tile per fused block

typedef float f32x4 __attribute__((ext_vector_type(4)));
typedef short bf16x8 __attribute__((ext_vector_type(8)));
typedef int   i32x4 __attribute__((ext_vector_type(4)));
typedef unsigned int u32x4 __attribute__((ext_vector_type(4)));

__device__ __forceinline__ ushort f2bf(float f) {
  union { float f; uint32_t u; } v; v.f = f;
  uint32_t r = v.u + 0x7FFFu + ((v.u >> 16) & 1u);   // RNE
  return (ushort)(r >> 16);
}
__device__ __forceinline__ float asf(uint32_t u) {
  union { uint32_t u; float f; } v; v.u = u; return v.f;
}

// K0 combined prep:
//  blocks [0,2048): x[b][c][n] f32 -> xT[b][n][c] bf16, b = bid&7 (XCD b owns
//                   batch b's slab; x reads are nontemporal to keep L2 clean).
//  blocks [2048,2112): W[o][c] f32 -> Wfrag[kc][o][ks] bf16 (kc=c/32, ks=c%32)
__global__ __launch_bounds__(256) void k_prep(
    const float* __restrict__ x, const float* __restrict__ W,
    ushort* __restrict__ xT, ushort* __restrict__ Wfrag)
{
  const int bid = blockIdx.x;
  const int t   = threadIdx.x;
  if (bid >= 2048) {                       // W conversion
    const int wb = bid - 2048;
    const int o  = wb * 4 + (t >> 6);
    const int k0 = (t & 63) * 4;
    f32x4 v = __builtin_nontemporal_load((const f32x4*)(W + (size_t)o * CC + k0));
    ushort4 h;
    h.x = f2bf(v.x); h.y = f2bf(v.y); h.z = f2bf(v.z); h.w = f2bf(v.w);
    const int kc = k0 >> 5, ks = k0 & 31;
    *(ushort4*)(Wfrag + ((size_t)(kc * CC + o)) * 32 + ks) = h;
    return;
  }
  __shared__ float tile[64][68];
  const int b    = bid & 7;                // XCD affinity (round-robin i%8)
  const int tl   = bid >> 3;               // 256 tiles per batch
  const int c0   = (tl & 3) * 64;
  const int n0   = (tl >> 2) * 64;
  {
    const int r  = t >> 2;
    const int cs = (t & 3) * 16;
    const float* xp = x + ((size_t)b * CC + c0 + r) * NN + n0 + cs;
    #pragma unroll
    for (int i = 0; i < 4; ++i) {
      f32x4 v = __builtin_nontemporal_load((const f32x4*)(xp + i * 4));
      *(f32x4*)&tile[r][cs + i * 4] = v;
    }
  }
  __syncthreads();
  const int nl = t >> 2;
  const int cl = (t & 3) * 16;
  union { ushort s[16]; uint4 q[2]; } pk;
  #pragma unroll
  for (int i = 0; i < 16; ++i) pk.s[i] = f2bf(tile[cl + i][nl]);
  uint4* dst = (uint4*)(xT + ((size_t)b * NN + n0 + nl) * CC + c0 + cl);
  dst[0] = pk.q[0];
  dst[1] = pk.q[1];
}

// K1 fused: gather+GIN update into LDS tile, then MFMA GEMM + bias + ReLU.
// blockIdx.x = tile*8 + b  (b = bid&7 -> same XCD that produced batch b's xT)
__global__ __launch_bounds__(256) void k_fused(
    const ushort* __restrict__ xT, const int* __restrict__ edge0,
    const float* __restrict__ eps, const ushort* __restrict__ Wfrag,
    const float* __restrict__ bias, float* __restrict__ out)
{
  __shared__ ushort hLds[NT][264];         // 528B row stride (33*16B: aligned)
  const int bid = blockIdx.x;
  const int b   = bid & 7;
  const int n0  = (bid >> 3) * NT;
  const int t    = threadIdx.x;
  const int wave = t >> 6, lane = t & 63;
  const float epsv = 1.0f + eps[0];
  const ushort* xb = xT + (size_t)b * NN * CC;

  // Phase 1: gather + GIN update -> hLds.
  // half-waves split two n-rows; each lane owns a channel octet (16B loads).
  // Accumulate as f32x4 (even/odd bf16 halves) -> v_pk_add_f32.
  const int half = lane >> 5;
  const int co   = (lane & 31) * 8;        // channel octet
  const uint32_t cb = (uint32_t)co;
  const int* ep_base = edge0 + ((size_t)b * NN) * KK;

  i32x4 e0, e1, e2, e3;
  {
    const i32x4* p = (const i32x4*)(ep_base + (size_t)(n0 + wave * 8 + half) * KK);
    e0 = __builtin_nontemporal_load(p + 0);
    e1 = __builtin_nontemporal_load(p + 1);
    e2 = __builtin_nontemporal_load(p + 2);
    e3 = __builtin_nontemporal_load(p + 3);
  }

  #pragma unroll
  for (int it = 0; it < 4; ++it) {
    const int nl = wave * 8 + it * 2 + half;
    const int n  = n0 + nl;
    // prefetch next iteration's edge indices (independent of this iter)
    i32x4 f0, f1, f2, f3;
    if (it < 3) {
      const i32x4* p = (const i32x4*)(ep_base + (size_t)(n + 2) * KK);
      f0 = __builtin_nontemporal_load(p + 0);
      f1 = __builtin_nontemporal_load(p + 1);
      f2 = __builtin_nontemporal_load(p + 2);
      f3 = __builtin_nontemporal_load(p + 3);
    }
    const uint32_t soff = ((uint32_t)n << 8) + cb;     // n*256 + co (elements)
    u32x4 sv = *(const u32x4*)(xb + soff);

    f32x4 accL = (f32x4){0.f, 0.f, 0.f, 0.f};          // even channels of octet
    f32x4 accH = (f32x4){0.f, 0.f, 0.f, 0.f};          // odd channels
    const int js[16] = {e0.x, e0.y, e0.z, e0.w, e1.x, e1.y, e1.z, e1.w,
                        e2.x, e2.y, e2.z, e2.w, e3.x, e3.y, e3.z, e3.w};
    #pragma unroll
    for (int k = 0; k < KK; ++k) {
      const uint32_t off = ((uint32_t)js[k] << 8) + cb;  // 32-bit voffset form
      u32x4 g = *(const u32x4*)(xb + off);
      f32x4 lo = (f32x4){asf(g.x << 16), asf(g.y << 16),
                         asf(g.z << 16), asf(g.w << 16)};
      f32x4 hi = (f32x4){asf(g.x & 0xffff0000u), asf(g.y & 0xffff0000u),
                         asf(g.z & 0xffff0000u), asf(g.w & 0xffff0000u)};
      accL += lo;
      accH += hi;
    }
    f32x4 sL = (f32x4){asf(sv.x << 16), asf(sv.y << 16),
                       asf(sv.z << 16), asf(sv.w << 16)};
    f32x4 sH = (f32x4){asf(sv.x & 0xffff0000u), asf(sv.y & 0xffff0000u),
                       asf(sv.z & 0xffff0000u), asf(sv.w & 0xffff0000u)};
    accL += sL * epsv;
    accH += sH * epsv;

    u32x4 pk;
    pk.x = (uint32_t)f2bf(accL[0]) | ((uint32_t)f2bf(accH[0]) << 16);
    pk.y = (uint32_t)f2bf(accL[1]) | ((uint32_t)f2bf(accH[1]) << 16);
    pk.z = (uint32_t)f2bf(accL[2]) | ((uint32_t)f2bf(accH[2]) << 16);
    pk.w = (uint32_t)f2bf(accL[3]) | ((uint32_t)f2bf(accH[3]) << 16);
    *(u32x4*)&hLds[nl][co] = pk;

    e0 = f0; e1 = f1; e2 = f2; e3 = f3;
  }
  __syncthreads();

  // Phase 2: GEMM. Wave w computes o in [w*64, w*64+64) x all NT n.
  f32x4 acc[4][NT / 16];
  #pragma unroll
  for (int m = 0; m < 4; ++m)
    #pragma unroll
    for (int nn = 0; nn < NT / 16; ++nn) acc[m][nn] = (f32x4){0.f, 0.f, 0.f, 0.f};

  const int lrow = lane & 15;
  const int kgrp = lane >> 4;
  const int o0   = wave * 64;

  #pragma unroll
  for (int kc = 0; kc < 8; ++kc) {
    const int cs = kgrp * 8;
    bf16x8 afr[4], bfr[NT / 16];
    #pragma unroll
    for (int m = 0; m < 4; ++m) {
      const uint32_t aoff = (uint32_t)(kc * CC + o0 + m * 16 + lrow) * 32 + cs;
      afr[m] = *(const bf16x8*)(Wfrag + aoff);
    }
    #pragma unroll
    for (int nn = 0; nn < NT / 16; ++nn)
      bfr[nn] = *(const bf16x8*)&hLds[nn * 16 + lrow][kc * 32 + cs];
    #pragma unroll
    for (int m = 0; m < 4; ++m)
      #pragma unroll
      for (int nn = 0; nn < NT / 16; ++nn)
        acc[m][nn] = __builtin_amdgcn_mfma_f32_16x16x32_bf16(
            afr[m], bfr[nn], acc[m][nn], 0, 0, 0);
  }

  // Epilogue: D col=lane&15 (n), row=(lane>>4)*4+r (o-local); bias + relu.
  // Nontemporal: out is touch-once, keep L2 for xT gathers of other blocks.
  #pragma unroll
  for (int m = 0; m < 4; ++m) {
    const f32x4 bv4 = *(const f32x4*)(bias + o0 + m * 16 + kgrp * 4);
    #pragma unroll
    for (int r = 0; r < 4; ++r) {
      const int o  = o0 + m * 16 + kgrp * 4 + r;
      #pragma unroll
      for (int nn = 0; nn < NT / 16; ++nn) {
        const int n = n0 + nn * 16 + lrow;
        float v = acc[m][nn][r] + bv4[r];
        v = v > 0.f ? v : 0.f;
        __builtin_nontemporal_store(v, &out[((size_t)b * CC + o) * NN + n]);
      }
    }
  }
}

extern "C" void kernel_launch(void* const* d_in, const int* in_sizes, int n_in,
                              void* d_out, int out_size, void* d_ws, size_t ws_size,
                              hipStream_t stream) {
  const float* x    = (const float*)d_in[0];
  const int*   edge = (const int*)d_in[1];   // [2][B][N][K] int32, plane 0 used
  const float* eps  = (const float*)d_in[2];
  const float* W    = (const float*)d_in[3];
  const float* bias = (const float*)d_in[4];
  float* out = (float*)d_out;

  ushort* xT    = (ushort*)d_ws;                         // [B][N][C] bf16, 16.8 MB
  ushort* Wfrag = xT + (size_t)BB * NN * CC;             // [8][C][32] bf16, 128 KB

  k_prep<<<2048 + 64, 256, 0, stream>>>(x, W, xT, Wfrag);

  k_fused<<<BB * (NN / NT), 256, 0, stream>>>(xT, edge, eps, Wfrag, bias, out);
}